// Round 2
// 223.693 us; speedup vs baseline: 1.1256x; 1.1256x over previous
//
#include <hip/hip_runtime.h>

#define N_NODES 50000
#define N_EDGES 600000
#define D 128
#define CAP 64   // fixed-capacity neighbor rows; P(deg>64) ~ 1e-26 for this graph, spill path keeps correctness anyway

typedef __attribute__((ext_vector_type(8))) short bf16x8;
typedef __attribute__((ext_vector_type(4))) float floatx4;

__device__ inline unsigned int f2bf(float f) {
    unsigned int u = __float_as_uint(f);
    return (u + 0x7FFFu + ((u >> 16) & 1u)) >> 16;   // RNE
}
__device__ inline float bf_lo(unsigned int u) { return __uint_as_float(u << 16); }
__device__ inline float bf_hi(unsigned int u) { return __uint_as_float(u & 0xFFFF0000u); }

// ---------------- fused prep: edge bucketing + cvt x -> bf16 + cvt W -> bf16 ----
// blocks [0,2344): edge bucketing (degree count + direct scatter into fixed-cap rows)
// blocks [2344,8594): x conversion (1 float4/thread) -> xbf (lives in d_out)
// blocks [8594,8850): weight conversion (4 * 128*128 elems)
__global__ void k_prep(const float* __restrict__ x, unsigned short* __restrict__ xbf,
                       const float* __restrict__ wa, const float* __restrict__ wb,
                       const float* __restrict__ wc, const float* __restrict__ wd,
                       unsigned short* __restrict__ wbf,
                       const int* __restrict__ src, const int* __restrict__ dst,
                       int* __restrict__ cnt, unsigned short* __restrict__ buf,
                       int* __restrict__ spillN, int* __restrict__ spillD,
                       int* __restrict__ spillS) {
    const int b = blockIdx.x;
    const int t = threadIdx.x;
    if (b < 2344) {
        int e = b * 256 + t;
        if (e < N_EDGES) {
            int d = dst[e], s = src[e];
            int p = atomicAdd(&cnt[d], 1);
            if (p < CAP) {
                buf[(size_t)d * CAP + p] = (unsigned short)s;   // src < 50000 fits u16
            } else {
                int k = atomicAdd(spillN, 1);
                spillD[k] = d; spillS[k] = s;
            }
        }
    } else if (b < 8594) {
        int i = (b - 2344) * 256 + t;
        float4 v = ((const float4*)x)[i];
        uint2 o;
        o.x = f2bf(v.x) | (f2bf(v.y) << 16);
        o.y = f2bf(v.z) | (f2bf(v.w) << 16);
        ((uint2*)xbf)[i] = o;
    } else {
        int i = (b - 8594) * 256 + t;
        const float* srcs[4] = {wa, wb, wc, wd};
        wbf[i] = (unsigned short)f2bf(srcs[i >> 14][i & 16383]);
    }
}

// ---------------- fused gather + MFMA layer ----------------
// Block = 256 threads = 16 nodes.
// Phase 1 (gather): thread (nl=t>>4, q=t&15) accumulates mean of node node0+nl,
//   cols [8q, 8q+8) in fp32; 16 consecutive lanes/node -> coalesced 256 B row
//   reads. Neighbor ids come from a dense 128 B fixed-capacity row. 8-deep
//   unrolled so 8 independent uint4 row loads are in flight per lane.
// Phase 2 (MFMA): wave wv computes feats [32*wv, 32*wv+32) for the 16 nodes.
//   A(mean) from LDS, A(x)/B(W rows) from global. Layouts = R6-validated:
//   A: lane=(l15,quad) -> row l15, k = quad*8 + kk*32 ; C/D: col=l15, row=quad*4+r.
#define ACC8(vv) do { \
    acc[0] += bf_lo((vv).x); acc[1] += bf_hi((vv).x); \
    acc[2] += bf_lo((vv).y); acc[3] += bf_hi((vv).y); \
    acc[4] += bf_lo((vv).z); acc[5] += bf_hi((vv).z); \
    acc[6] += bf_lo((vv).w); acc[7] += bf_hi((vv).w); } while (0)

template <bool RELU, bool OUT_BF16>
__global__ void __launch_bounds__(256) k_gather_layer(
    const int* __restrict__ cnt, const unsigned short* __restrict__ buf,
    const int* __restrict__ spillN, const int* __restrict__ spillD,
    const int* __restrict__ spillS,
    const unsigned short* __restrict__ Xbf,
    const unsigned short* __restrict__ Wlbf, const float* __restrict__ bias,
    const unsigned short* __restrict__ Wrbf, void* __restrict__ outp) {
    __shared__ unsigned short tile[16][136];   // 272 B row stride (16B-mult)

    const int t = threadIdx.x;
    const int node0 = blockIdx.x * 16;         // grid 3125 -> exact

    // ---- phase 1: gather mean ----
    {
        const int nl = t >> 4, q = t & 15;
        const int node = node0 + nl;
        const int deg = cnt[node];
        const int m = deg < CAP ? deg : CAP;
        const unsigned short* __restrict__ nb = buf + (size_t)node * CAP;
        float acc[8] = {0.f, 0.f, 0.f, 0.f, 0.f, 0.f, 0.f, 0.f};
        int e = 0;
        for (; e + 8 <= m; e += 8) {
            uint4 v[8];
#pragma unroll
            for (int u = 0; u < 8; ++u)
                v[u] = *(const uint4*)(Xbf + (size_t)nb[e + u] * D + q * 8);
#pragma unroll
            for (int u = 0; u < 8; ++u) ACC8(v[u]);
        }
        for (; e + 4 <= m; e += 4) {
            uint4 v[4];
#pragma unroll
            for (int u = 0; u < 4; ++u)
                v[u] = *(const uint4*)(Xbf + (size_t)nb[e + u] * D + q * 8);
#pragma unroll
            for (int u = 0; u < 4; ++u) ACC8(v[u]);
        }
        for (; e < m; ++e) {
            uint4 v = *(const uint4*)(Xbf + (size_t)nb[e] * D + q * 8);
            ACC8(v);
        }
        if (deg > CAP) {                       // correctness-only path; never taken for this graph
            int sn = *spillN;
            for (int k = 0; k < sn; ++k) {
                if (spillD[k] == node) {
                    uint4 v = *(const uint4*)(Xbf + (size_t)spillS[k] * D + q * 8);
                    ACC8(v);
                }
            }
        }
        float inv = (deg > 0) ? 1.0f / (float)deg : 0.0f;
        uint4 o;
        o.x = f2bf(acc[0] * inv) | (f2bf(acc[1] * inv) << 16);
        o.y = f2bf(acc[2] * inv) | (f2bf(acc[3] * inv) << 16);
        o.z = f2bf(acc[4] * inv) | (f2bf(acc[5] * inv) << 16);
        o.w = f2bf(acc[6] * inv) | (f2bf(acc[7] * inv) << 16);
        *(uint4*)(&tile[nl][q * 8]) = o;
    }
    __syncthreads();

    // ---- phase 2: MFMA ----
    const int lane = t & 63;
    const int wv = t >> 6;                 // wave id 0..3 -> feats [32wv, 32wv+32)
    const int l15 = lane & 15;
    const int quad = lane >> 4;

    floatx4 c0 = (floatx4)(0.f), c1 = (floatx4)(0.f);
    const int nf0 = wv * 2, nf1 = wv * 2 + 1;

    const unsigned short* mrow = &tile[l15][quad * 8];
    const unsigned short* arowX = Xbf + (size_t)(node0 + l15) * D + quad * 8;

#pragma unroll
    for (int kk = 0; kk < 4; ++kk) {
        bf16x8 a = *(const bf16x8*)(mrow + kk * 32);
        bf16x8 b0 = *(const bf16x8*)(Wlbf + (size_t)(nf0 * 16 + l15) * D + kk * 32 + quad * 8);
        bf16x8 b1 = *(const bf16x8*)(Wlbf + (size_t)(nf1 * 16 + l15) * D + kk * 32 + quad * 8);
        c0 = __builtin_amdgcn_mfma_f32_16x16x32_bf16(a, b0, c0, 0, 0, 0);
        c1 = __builtin_amdgcn_mfma_f32_16x16x32_bf16(a, b1, c1, 0, 0, 0);
    }
#pragma unroll
    for (int kk = 0; kk < 4; ++kk) {
        bf16x8 a = *(const bf16x8*)(arowX + kk * 32);
        bf16x8 b0 = *(const bf16x8*)(Wrbf + (size_t)(nf0 * 16 + l15) * D + kk * 32 + quad * 8);
        bf16x8 b1 = *(const bf16x8*)(Wrbf + (size_t)(nf1 * 16 + l15) * D + kk * 32 + quad * 8);
        c0 = __builtin_amdgcn_mfma_f32_16x16x32_bf16(a, b0, c0, 0, 0, 0);
        c1 = __builtin_amdgcn_mfma_f32_16x16x32_bf16(a, b1, c1, 0, 0, 0);
    }

#pragma unroll
    for (int j = 0; j < 2; ++j) {
        floatx4 c = j ? c1 : c0;
        int f = (wv * 2 + j) * 16 + l15;
        float bv = bias[f];
#pragma unroll
        for (int r = 0; r < 4; ++r) {
            float v = c[r] + bv;
            if (RELU) v = v > 0.f ? v : 0.2f * v;
            int node = node0 + quad * 4 + r;
            if (OUT_BF16)
                ((unsigned short*)outp)[(size_t)node * D + f] = (unsigned short)f2bf(v);
            else
                ((float*)outp)[(size_t)node * D + f] = v;
        }
    }
}

// ---------------- host launch ----------------

extern "C" void kernel_launch(void* const* d_in, const int* in_sizes, int n_in,
                              void* d_out, int out_size, void* d_ws, size_t ws_size,
                              hipStream_t stream) {
    (void)in_sizes; (void)n_in; (void)out_size; (void)ws_size;

    const float* x   = (const float*)d_in[0];
    const int*   ei  = (const int*)d_in[1];
    const float* W1l = (const float*)d_in[2];
    const float* b1  = (const float*)d_in[3];
    const float* W1r = (const float*)d_in[4];
    const float* W2l = (const float*)d_in[5];
    const float* b2  = (const float*)d_in[6];
    const float* W2r = (const float*)d_in[7];

    const int* src = ei;
    const int* dst = ei + N_EDGES;

    char* ws = (char*)d_ws;
    int* cnt              = (int*)(ws + 0);                  // 200,000 B
    int* spillN           = (int*)(ws + 200000);             // 4 B (zeroed with cnt)
    int* spillD           = (int*)(ws + 200064);             // 2,400,000 B
    int* spillS           = (int*)(ws + 2600064);            // 2,400,000 B
    unsigned short* buf   = (unsigned short*)(ws + 5000064); // 6,400,000 B (50000*64 u16)
    unsigned short* wbf   = (unsigned short*)(ws + 11400064);// 131,072 B
    unsigned short* hbf   = (unsigned short*)(ws + 11531136);// 12,800,000 B  (ends 24.3 MB)

    // xbf lives in d_out (25.6 MB): layer 2 never reads x, so the final fp32
    // output write may clobber it.
    unsigned short* xbf = (unsigned short*)d_out;
    float* out = (float*)d_out;

    unsigned short* w1l_bf = wbf;
    unsigned short* w1r_bf = wbf + 16384;
    unsigned short* w2l_bf = wbf + 32768;
    unsigned short* w2r_bf = wbf + 49152;

    hipMemsetAsync(ws, 0, 200064, stream);   // cnt + spillN

    k_prep<<<8850, 256, 0, stream>>>(x, xbf, W1l, W1r, W2l, W2r, wbf,
                                     src, dst, cnt, buf, spillN, spillD, spillS);

    k_gather_layer<true, true><<<N_NODES / 16, 256, 0, stream>>>(
        cnt, buf, spillN, spillD, spillS, xbf, w1l_bf, b1, w1r_bf, (void*)hbf);
    k_gather_layer<false, false><<<N_NODES / 16, 256, 0, stream>>>(
        cnt, buf, spillN, spillD, spillS, hbf, w2l_bf, b2, w2r_bf, (void*)out);
}